// Round 7
// baseline (264.796 us; speedup 1.0000x reference)
//
#include <hip/hip_runtime.h>
#include <hip/hip_bf16.h>

#define PTOT   1048576
#define NRAYS  8192
#define THRESH 1e-4f

typedef float F2  __attribute__((ext_vector_type(2)));
typedef short S8  __attribute__((ext_vector_type(8)));   // bf16x8 MFMA frag (4 VGPR)
typedef float F4v __attribute__((ext_vector_type(4)));   // MFMA acc

__device__ __forceinline__ F2 f2splat(float s){ F2 r; r.x = s; r.y = s; return r; }
__device__ __forceinline__ F2 f2fma(F2 a, float b, F2 c){
    return __builtin_elementwise_fma(a, f2splat(b), c);
}
__device__ __forceinline__ float raw2alpha_f(float d){
    // 1 - exp(-softplus(d - 4) * 0.5) == 1 - (1 + e^(d-4))^(-1/2)
    return 1.0f - rsqrtf(1.0f + __expf(d - 4.0f));
}
__device__ __forceinline__ unsigned f2bf(float f){   // fp32 -> bf16 bits (RNE)
    unsigned u = __float_as_uint(f);
    return (u + 0x7FFFu + ((u >> 16) & 1u)) >> 16;
}
union HB2 { __hip_bfloat162 h; unsigned u; };

// ---------------- kernel 1: per-point density alpha + gate + bf16 feature vec ----------------
__global__ __launch_bounds__(256) void k_point(
    const float* __restrict__ pts, const float* __restrict__ vdirs,
    const int* __restrict__ ray_id,
    const float* __restrict__ Wd1, const float* __restrict__ bd1,
    const float* __restrict__ Wd2, const float* __restrict__ Wg,
    float* __restrict__ alpha0, float* __restrict__ g0a, int* __restrict__ eea,
    int4* __restrict__ xq)
{
    __shared__ float4 WD4[128];   // {Wd1[0][i], Wd1[1][i], Wd1[2][i], bd1[i]}
    __shared__ float  WD2s[128];
    __shared__ float  WGs[8][6];
    int t = threadIdx.x;
    if (t < 128){
        WD4[t] = make_float4(Wd1[t], Wd1[128+t], Wd1[256+t], bd1[t]);
        WD2s[t] = Wd2[t];
    }
    if (t < 48) WGs[t & 7][t >> 3] = Wg[t];   // Wg[k][e] flat = k*8+e
    __syncthreads();

    int base = blockIdx.x * 2048 + t;         // 8 points/thread as 4 F2 pairs
    F2 px[4], py[4], pz[4], vx[4], vy[4], vz[4], dens[4];
    #pragma unroll
    for (int q=0;q<4;q++){
        int p0 = base + (2*q)*256, p1 = p0 + 256;
        px[q] = (F2){pts[3*p0],   pts[3*p1]};
        py[q] = (F2){pts[3*p0+1], pts[3*p1+1]};
        pz[q] = (F2){pts[3*p0+2], pts[3*p1+2]};
        int r0 = ray_id[p0], r1 = ray_id[p1];
        vx[q] = (F2){vdirs[3*r0],   vdirs[3*r1]};
        vy[q] = (F2){vdirs[3*r0+1], vdirs[3*r1+1]};
        vz[q] = (F2){vdirs[3*r0+2], vdirs[3*r1+2]};
        dens[q] = f2splat(0.f);
    }
    #pragma unroll 2
    for (int i=0;i<128;i++){
        float4 w = WD4[i]; float w2 = WD2s[i];
        #pragma unroll
        for (int q=0;q<4;q++){
            F2 h = f2fma(px[q], w.x, f2fma(py[q], w.y, f2fma(pz[q], w.z, f2splat(w.w))));
            h = __builtin_elementwise_max(h, f2splat(0.f));
            dens[q] = f2fma(h, w2, dens[q]);
        }
    }
    #pragma unroll
    for (int q=0;q<4;q++){
        float a0 = raw2alpha_f(dens[q].x);
        float a1 = raw2alpha_f(dens[q].y);
        alpha0[base + (2*q)*256]   = (a0 > THRESH) ? a0 : 0.f;
        alpha0[base + (2*q+1)*256] = (a1 > THRESH) ? a1 : 0.f;
    }
    // bf16 feature vector {x,y,z,vx,vy,vz,1,0} per point (feeds MFMA expert kernel)
    #pragma unroll
    for (int q=0;q<4;q++){
        #pragma unroll
        for (int s=0;s<2;s++){
            float fx = s? px[q].y:px[q].x, fy = s? py[q].y:py[q].x, fz = s? pz[q].y:pz[q].x;
            float gx = s? vx[q].y:vx[q].x, gy = s? vy[q].y:vy[q].x, gz = s? vz[q].y:vz[q].x;
            int4 v;
            v.x = (int)(f2bf(fx) | (f2bf(fy) << 16));
            v.y = (int)(f2bf(fz) | (f2bf(gx) << 16));
            v.z = (int)(f2bf(gy) | (f2bf(gz) << 16));
            v.w = (int)0x3F80u;                     // {1.0bf16, 0}
            xq[base + (2*q+s)*256] = v;
        }
    }
    // gate: top-2 of softmax over 8 experts, renormalized
    float m0[8], m1[8]; int i0[8], i1[8];
    #pragma unroll
    for (int j=0;j<8;j++){ m0[j]=-3.0e38f; m1[j]=-3.0e38f; i0[j]=0; i1[j]=0; }
    for (int e=0;e<8;e++){
        float w0=WGs[e][0],w1=WGs[e][1],w2=WGs[e][2],w3=WGs[e][3],w4=WGs[e][4],w5=WGs[e][5];
        #pragma unroll
        for (int q=0;q<4;q++){
            F2 l = f2fma(px[q],w0, f2fma(py[q],w1, f2fma(pz[q],w2,
                   f2fma(vx[q],w3, f2fma(vy[q],w4,
                   __builtin_elementwise_fma(vz[q], f2splat(w5), f2splat(0.f)))))));
            int j0 = 2*q, j1 = 2*q+1;
            float lx = l.x, ly = l.y;
            if (lx > m0[j0]){ m1[j0]=m0[j0]; i1[j0]=i0[j0]; m0[j0]=lx; i0[j0]=e; }
            else if (lx > m1[j0]){ m1[j0]=lx; i1[j0]=e; }
            if (ly > m0[j1]){ m1[j1]=m0[j1]; i1[j1]=i0[j1]; m0[j1]=ly; i0[j1]=e; }
            else if (ly > m1[j1]){ m1[j1]=ly; i1[j1]=e; }
        }
    }
    #pragma unroll
    for (int j=0;j<8;j++){
        float g0 = __fdividef(1.0f, 1.0f + __expf(m1[j]-m0[j]));
        g0a[base + j*256] = g0;
        eea[base + j*256] = i0[j] | (i1[j] << 8);
    }
}

// ---------------- kernel 2: ray start offsets (binary search) ----------------
__global__ __launch_bounds__(256) void k_rayoff(const int* __restrict__ ray_id,
                                                int* __restrict__ ray_off)
{
    int r = blockIdx.x*256 + threadIdx.x;
    if (r > NRAYS) return;
    int lo = 0, hi = PTOT;
    while (lo < hi){ int mid = (lo+hi) >> 1; if (ray_id[mid] < r) lo = mid+1; else hi = mid; }
    ray_off[r] = lo;
}

// ---------------- kernel 3: transmittance scan -> keep mask + expert counts ----------------
__global__ __launch_bounds__(256) void k_scan0(const float* __restrict__ alpha0,
                                               const int* __restrict__ eea,
                                               const int* __restrict__ ray_off,
                                               unsigned char* __restrict__ keep,
                                               int* __restrict__ cntA)
{
    __shared__ int wcs[4][8];
    int t = threadIdx.x, lane = t & 63, w = t >> 6;
    int wid = blockIdx.x*4 + w;                      // wave = ray
    int c[8];
    #pragma unroll
    for (int e=0;e<8;e++) c[e]=0;
    int s = ray_off[wid], e = ray_off[wid+1];
    float carry = 1.f;
    for (int ch = s; ch < e; ch += 64){
        int p = ch + lane;
        bool in = p < e;
        float a = in ? alpha0[p] : 0.f;
        int  ee = in ? eea[p] : 0;
        float incl = 1.f - a;
        #pragma unroll
        for (int d=1; d<64; d<<=1){ float tt = __shfl_up(incl, d); if (lane >= d) incl *= tt; }
        float excl = __shfl_up(incl, 1); if (lane == 0) excl = 1.f;
        float w0 = a * carry * excl;
        int k = (in && w0 > THRESH) ? 1 : 0;
        if (in) keep[p] = (unsigned char)k;
        int e0 = ee & 255, e1 = (ee >> 8) & 255;
        #pragma unroll
        for (int x=0;x<8;x++){
            unsigned long long m0 = __ballot(k && e0==x);
            unsigned long long m1 = __ballot(k && e1==x);
            c[x] += __popcll(m0) + __popcll(m1);
        }
        carry *= __shfl(incl, 63);
    }
    if (lane == 0){
        #pragma unroll
        for (int x=0;x<8;x++) wcs[w][x] = c[x];
    }
    __syncthreads();
    if (t < 8){
        int sum = wcs[0][t]+wcs[1][t]+wcs[2][t]+wcs[3][t];
        if (sum) atomicAdd(&cntA[t], sum);
    }
}

// ---------------- kernel 4b: exclusive prefix offsets ----------------
__global__ void k_offsets(const int* __restrict__ cntA,
                          int* __restrict__ offA, int* __restrict__ curA)
{
    if (threadIdx.x == 0 && blockIdx.x == 0){
        int acc = 0;
        for (int e = 0; e < 8; e++){ offA[e] = acc; acc += cntA[e]; curA[e] = 0; }
    }
}

// ---------------- kernel 4c: fill entries (ballot-ranked, exact) ----------------
// entry.x = pid | (slot << 30), entry.y = gate weight bits
__global__ __launch_bounds__(256) void k_fill(const unsigned char* __restrict__ keep,
                                              const float* __restrict__ g0a,
                                              const int* __restrict__ eea,
                                              const int* __restrict__ offA,
                                              int* __restrict__ curA,
                                              int2* __restrict__ ent)
{
    __shared__ int wc[4][8];
    __shared__ int wb[4][8];
    int t = threadIdx.x, lane = t & 63, w = t >> 6;
    unsigned long long lt = (1ull << lane) - 1ull;
    int base = blockIdx.x * 2048;

    int c[8];
    #pragma unroll
    for (int e=0;e<8;e++) c[e]=0;
    for (int j=0;j<8;j++){
        int p = base + (j*4 + w)*64 + lane;
        int k = keep[p];
        int ee = eea[p];
        int e0 = ee & 255, e1 = (ee >> 8) & 255;
        #pragma unroll
        for (int e=0;e<8;e++){
            unsigned long long m0 = __ballot(k && e0==e);
            unsigned long long m1 = __ballot(k && e1==e);
            c[e] += __popcll(m0) + __popcll(m1);
        }
    }
    if (lane == 0){
        #pragma unroll
        for (int e=0;e<8;e++) wc[w][e] = c[e];
    }
    __syncthreads();
    if (t < 8){
        int tot = wc[0][t]+wc[1][t]+wc[2][t]+wc[3][t];
        int b = offA[t] + (tot ? atomicAdd(&curA[t], tot) : 0);
        wb[0][t] = b; b += wc[0][t];
        wb[1][t] = b; b += wc[1][t];
        wb[2][t] = b; b += wc[2][t];
        wb[3][t] = b;
    }
    __syncthreads();

    int cur[8];
    #pragma unroll
    for (int e=0;e<8;e++) cur[e] = wb[w][e];
    for (int j=0;j<8;j++){
        int p = base + (j*4 + w)*64 + lane;
        int k = keep[p];
        float g0 = g0a[p];
        int ee = eea[p];
        int e0 = ee & 255, e1 = (ee >> 8) & 255;
        #pragma unroll
        for (int e=0;e<8;e++){
            unsigned long long m0 = __ballot(k && e0==e);
            unsigned long long m1 = __ballot(k && e1==e);
            if (k && e0==e)
                ent[cur[e] + __popcll(m0 & lt)] = make_int2(p, __float_as_int(g0));
            if (k && e1==e)
                ent[cur[e] + __popcll(m0) + __popcll(m1 & lt)] =
                    make_int2(p | (1 << 30), __float_as_int(1.0f - g0));
            cur[e] += __popcll(m0) + __popcll(m1);
        }
    }
}

// ---------------- kernel 5: expert MLPs via bf16 MFMA ----------------
// 1024 blocks/expert, 256 threads = 4 independent waves; per wave 4 chunks of 64
// entries (4 tiles of 16). GEMM1 transposed (A=W1[hidden x 7], B=x[7 x entry])
// so H exits with col=entry; relu+cvt -> per-wave-private LDS -> A-frag of GEMM2.
// No __syncthreads anywhere in the main loop.
// R6 bug fixed: entry fetch must be offA[e] + expert-relative idx.
__global__ __launch_bounds__(256) void k_expert(
    const int2* __restrict__ ent, const int* __restrict__ cntA,
    const int* __restrict__ offA, const int4* __restrict__ xq,
    const float* __restrict__ We1, const float* __restrict__ be1,
    const float* __restrict__ Wrgb, const float* __restrict__ Walpha,
    float* __restrict__ resf)
{
    int e    = blockIdx.x >> 10;
    int bi   = blockIdx.x & 1023;
    int n    = cntA[e];
    int base = bi * 1024;
    if (base >= n) return;
    int t = threadIdx.x, lane = t & 63, w = t >> 6;
    int c16 = lane & 15, quad = lane >> 4;
    const int2* eb = ent + offA[e];          // <-- the R6 fix

    // --- preload GEMM1 A-frags: A[m=hid%16][k=quad*8+j], k<6 -> We1, k==6 -> be1 ---
    S8 A1[8];
    #pragma unroll
    for (int mt=0; mt<8; mt++){
        S8 f = (S8)0;
        if (quad == 0){
            int hid = mt*16 + c16;
            #pragma unroll
            for (int j=0;j<6;j++) f[j] = (short)f2bf(We1[e*768 + j*128 + hid]);
            f[6] = (short)f2bf(be1[e*128 + hid]);
        }
        A1[mt] = f;
    }
    // --- preload GEMM2 B-frags: B[k2=32s+quad*8+j][n=c16]; n<3 Wrgb, n==3 Walpha ---
    S8 B2[4];
    #pragma unroll
    for (int s=0;s<4;s++){
        S8 f = (S8)0;
        if (c16 < 4){
            #pragma unroll
            for (int j=0;j<8;j++){
                int k2 = s*32 + quad*8 + j;
                float v = (c16 < 3) ? Wrgb[e*384 + k2*3 + c16] : Walpha[e*128 + k2];
                f[j] = (short)f2bf(v);
            }
        }
        B2[s] = f;
    }

    __shared__ short Hlds[4][16][136];   // per-wave private: 16 entries x 128 hidden (+pad)
    short* hbase = &Hlds[w][0][0];
    const F4v zf = {0.f, 0.f, 0.f, 0.f};

    for (int chunk = 0; chunk < 4; chunk++){
        int cbase = base + w*256 + chunk*64;
        if (cbase >= n) break;
        int idx = cbase + lane;
        int2 rec = (idx < n) ? eb[idx] : make_int2(PTOT, 0);
        int4 xv  = xq[rec.x & 0x0FFFFFFF];
        float g  = __int_as_float(rec.y);

        #pragma unroll
        for (int t4=0; t4<4; t4++){
            // B1-frag: quad0 lanes hold xq of entry t4*16+c16 (cross-lane fetch)
            int src = t4*16 + c16;
            union { int4 i; S8 s; } bu;
            bu.i.x = __shfl(xv.x, src); bu.i.y = __shfl(xv.y, src);
            bu.i.z = __shfl(xv.z, src); bu.i.w = __shfl(xv.w, src);
            S8 bfrag = (quad == 0) ? bu.s : (S8)0;

            // GEMM1: H[hid][entry] tiles; lane -> H[16mt+4quad+r][c16]
            #pragma unroll
            for (int mt=0; mt<8; mt++){
                F4v h = __builtin_amdgcn_mfma_f32_16x16x32_bf16(A1[mt], bfrag, zf, 0, 0, 0);
                HB2 p0, p1;
                p0.h = __float22bfloat162_rn(make_float2(fmaxf(h[0],0.f), fmaxf(h[1],0.f)));
                p1.h = __float22bfloat162_rn(make_float2(fmaxf(h[2],0.f), fmaxf(h[3],0.f)));
                int ofs = c16*136 + mt*16 + quad*4;          // in shorts, 8B aligned
                *(int2*)(hbase + ofs) = make_int2((int)p0.u, (int)p1.u);
            }
            // GEMM2: O[entry][out] = relu(H) @ [Wrgb|Walpha]
            F4v o = zf;
            #pragma unroll
            for (int s=0;s<4;s++){
                S8 a2 = *(const S8*)(hbase + c16*136 + s*32 + quad*8);  // 16B aligned
                o = __builtin_amdgcn_mfma_f32_16x16x32_bf16(a2, B2[s], o, 0, 0, 0);
            }
            // epilogue: lane holds O[entry=4*quad+r][out=c16] (c16<4 useful)
            float ge[4]; int pe[4];
            #pragma unroll
            for (int r=0;r<4;r++){
                int elane = t4*16 + quad*4 + r;
                ge[r] = __shfl(g, elane);
                pe[r] = __shfl(rec.x, elane);
            }
            if (c16 < 4){
                #pragma unroll
                for (int r=0;r<4;r++){
                    float v = o[r];
                    float outv = (c16 == 3) ? raw2alpha_f(v)
                               : __fdividef(1.0f, 1.0f + __expf(-v));
                    int pp = pe[r] & 0x0FFFFFFF;
                    int sl = ((unsigned)pe[r]) >> 30;
                    resf[(size_t)(2*pp + sl)*4 + c16] = ge[r] * outv;
                }
            }
        }
    }
}

// ---------------- kernel 6: final per-ray composite ----------------
__global__ __launch_bounds__(256) void k_scan1(const float4* __restrict__ res,
                                               const unsigned char* __restrict__ keep,
                                               const int* __restrict__ ray_off,
                                               const float* __restrict__ bg,
                                               float* __restrict__ out)
{
    int wid  = (blockIdx.x*blockDim.x + threadIdx.x) >> 6;   // wave = ray
    int lane = threadIdx.x & 63;
    if (wid >= NRAYS) return;
    int s = ray_off[wid], e = ray_off[wid+1];
    float carry = 1.f;
    float accx = 0.f, accy = 0.f, accz = 0.f;
    for (int c = s; c < e; c += 64){
        int p = c + lane;
        float4 v = make_float4(0.f,0.f,0.f,0.f);
        if (p < e && keep[p]){
            float4 v0 = res[2*(size_t)p];
            float4 v1 = res[2*(size_t)p + 1];
            v = make_float4(v0.x+v1.x, v0.y+v1.y, v0.z+v1.z, v0.w+v1.w);
        }
        float a = v.w;
        float incl = 1.f - a;
        #pragma unroll
        for (int d=1; d<64; d<<=1){ float tt = __shfl_up(incl, d); if (lane >= d) incl *= tt; }
        float excl = __shfl_up(incl, 1); if (lane == 0) excl = 1.f;
        float w = a * carry * excl;
        accx = fmaf(w, v.x, accx);
        accy = fmaf(w, v.y, accy);
        accz = fmaf(w, v.z, accz);
        carry *= __shfl(incl, 63);
    }
    #pragma unroll
    for (int d=32; d; d>>=1){
        accx += __shfl_xor(accx, d);
        accy += __shfl_xor(accy, d);
        accz += __shfl_xor(accz, d);
    }
    if (lane == 0){
        out[3*wid+0] = accx + carry*bg[0];
        out[3*wid+1] = accy + carry*bg[1];
        out[3*wid+2] = accz + carry*bg[2];
    }
}

extern "C" void kernel_launch(void* const* d_in, const int* in_sizes, int n_in,
                              void* d_out, int out_size, void* d_ws, size_t ws_size,
                              hipStream_t stream)
{
    const float* pts    = (const float*)d_in[0];
    const float* vdirs  = (const float*)d_in[1];
    const float* bg     = (const float*)d_in[2];
    const float* Wd1    = (const float*)d_in[3];
    const float* bd1    = (const float*)d_in[4];
    const float* Wd2    = (const float*)d_in[5];
    const float* Wg     = (const float*)d_in[6];
    const float* We1    = (const float*)d_in[7];
    const float* be1    = (const float*)d_in[8];
    const float* Wrgb   = (const float*)d_in[9];
    const float* Walpha = (const float*)d_in[10];
    const int*   ray_id = (const int*)d_in[11];
    float* out = (float*)d_out;

    char* ws = (char*)d_ws;
    size_t off = 0;
    float* alpha0        = (float*)(ws + off); off += (size_t)PTOT*4;     // 4MB
    float* g0a           = (float*)(ws + off); off += (size_t)PTOT*4;     // 4MB
    int*   eea           = (int*)  (ws + off); off += (size_t)PTOT*4;     // 4MB
    unsigned char* keep  = (unsigned char*)(ws + off); off += (size_t)PTOT; // 1MB
    int*   ray_off       = (int*)  (ws + off); off += 65536;
    int*   cntA          = (int*)  (ws + off); off += 256;
    int*   offA          = (int*)  (ws + off); off += 256;
    int*   curA          = (int*)  (ws + off); off += 256;
    off = (off + 255) & ~(size_t)255;
    int4*  xq            = (int4*) (ws + off); off += ((size_t)PTOT+1)*16; // 16MB bf16 features
    int2*  ent           = (int2*) (ws + off); off += (size_t)2*PTOT*8;    // 16MB
    float4* res          = (float4*)(ws + off); off += ((size_t)2*PTOT+2)*16; // 32MB

    hipMemsetAsync(cntA, 0, 8*sizeof(int), stream);

    k_point  <<<PTOT/2048, 256, 0, stream>>>(pts, vdirs, ray_id, Wd1, bd1, Wd2, Wg,
                                             alpha0, g0a, eea, xq);
    k_rayoff <<<(NRAYS+256)/256, 256, 0, stream>>>(ray_id, ray_off);
    k_scan0  <<<NRAYS/4, 256, 0, stream>>>(alpha0, eea, ray_off, keep, cntA);
    k_offsets<<<1, 64, 0, stream>>>(cntA, offA, curA);
    k_fill   <<<PTOT/2048, 256, 0, stream>>>(keep, g0a, eea, offA, curA, ent);
    k_expert <<<8*1024, 256, 0, stream>>>(ent, cntA, offA, xq,
                                          We1, be1, Wrgb, Walpha, (float*)res);
    k_scan1  <<<NRAYS*64/256, 256, 0, stream>>>(res, keep, ray_off, bg, out);
}

// Round 8
// 249.098 us; speedup vs baseline: 1.0630x; 1.0630x over previous
//
#include <hip/hip_runtime.h>

#define PTOT   1048576
#define NRAYS  8192
#define THRESH 1e-4f

typedef float F2 __attribute__((ext_vector_type(2)));

__device__ __forceinline__ F2 f2splat(float s){ F2 r; r.x = s; r.y = s; return r; }
__device__ __forceinline__ F2 f2fma(F2 a, float b, F2 c){
    return __builtin_elementwise_fma(a, f2splat(b), c);
}
__device__ __forceinline__ float raw2alpha_f(float d){
    // 1 - exp(-softplus(d - 4) * 0.5) == 1 - (1 + e^(d-4))^(-1/2)
    return 1.0f - rsqrtf(1.0f + __expf(d - 4.0f));
}

// ---------------- kernel 1: density alpha + gate + vd cache + ray_off ----------------
__global__ __launch_bounds__(256) void k_point(
    const float* __restrict__ pts, const float* __restrict__ vdirs,
    const int* __restrict__ ray_id,
    const float* __restrict__ Wd1, const float* __restrict__ bd1,
    const float* __restrict__ Wd2, const float* __restrict__ Wg,
    float* __restrict__ alpha0, float* __restrict__ g0a, int* __restrict__ eea,
    float4* __restrict__ vd, int* __restrict__ ray_off)
{
    __shared__ float4 WD4[128];   // {Wd1[0][i], Wd1[1][i], Wd1[2][i], bd1[i]}
    __shared__ float  WD2s[128];
    __shared__ float  WGs[8][6];
    int t = threadIdx.x;
    if (t < 128){
        WD4[t] = make_float4(Wd1[t], Wd1[128+t], Wd1[256+t], bd1[t]);
        WD2s[t] = Wd2[t];
    }
    if (t < 48) WGs[t & 7][t >> 3] = Wg[t];   // Wg[k][e] flat = k*8+e
    __syncthreads();

    int base = blockIdx.x * 2048 + t;         // 8 points/thread as 4 F2 pairs
    F2 px[4], py[4], pz[4], vx[4], vy[4], vz[4], dens[4];
    int rid0[4], rid1[4];
    #pragma unroll
    for (int q=0;q<4;q++){
        int p0 = base + (2*q)*256, p1 = p0 + 256;
        px[q] = (F2){pts[3*p0],   pts[3*p1]};
        py[q] = (F2){pts[3*p0+1], pts[3*p1+1]};
        pz[q] = (F2){pts[3*p0+2], pts[3*p1+2]};
        int r0 = ray_id[p0], r1 = ray_id[p1];
        rid0[q] = r0; rid1[q] = r1;
        vx[q] = (F2){vdirs[3*r0],   vdirs[3*r1]};
        vy[q] = (F2){vdirs[3*r0+1], vdirs[3*r1+1]};
        vz[q] = (F2){vdirs[3*r0+2], vdirs[3*r1+2]};
        dens[q] = f2splat(0.f);
    }
    // vd cache (one coalesced float4 per point) + ray segment boundaries
    #pragma unroll
    for (int q=0;q<4;q++){
        int p0 = base + (2*q)*256, p1 = p0 + 256;
        vd[p0] = make_float4(vx[q].x, vy[q].x, vz[q].x, 0.f);
        vd[p1] = make_float4(vx[q].y, vy[q].y, vz[q].y, 0.f);
        int prev0 = (p0 == 0) ? -1 : ray_id[p0-1];
        if (prev0 != rid0[q]) for (int r=prev0+1; r<=rid0[q]; ++r) ray_off[r] = p0;
        int prev1 = ray_id[p1-1];
        if (prev1 != rid1[q]) for (int r=prev1+1; r<=rid1[q]; ++r) ray_off[r] = p1;
        if (p1 == PTOT-1) for (int r=rid1[q]+1; r<=NRAYS; ++r) ray_off[r] = PTOT;
    }
    #pragma unroll 2
    for (int i=0;i<128;i++){
        float4 w = WD4[i]; float w2 = WD2s[i];
        #pragma unroll
        for (int q=0;q<4;q++){
            F2 h = f2fma(px[q], w.x, f2fma(py[q], w.y, f2fma(pz[q], w.z, f2splat(w.w))));
            h = __builtin_elementwise_max(h, f2splat(0.f));
            dens[q] = f2fma(h, w2, dens[q]);
        }
    }
    #pragma unroll
    for (int q=0;q<4;q++){
        float a0 = raw2alpha_f(dens[q].x);
        float a1 = raw2alpha_f(dens[q].y);
        alpha0[base + (2*q)*256]   = (a0 > THRESH) ? a0 : 0.f;
        alpha0[base + (2*q+1)*256] = (a1 > THRESH) ? a1 : 0.f;
    }
    // gate: top-2 of softmax over 8 experts, renormalized
    float m0[8], m1[8]; int i0[8], i1[8];
    #pragma unroll
    for (int j=0;j<8;j++){ m0[j]=-3.0e38f; m1[j]=-3.0e38f; i0[j]=0; i1[j]=0; }
    for (int e=0;e<8;e++){
        float w0=WGs[e][0],w1=WGs[e][1],w2=WGs[e][2],w3=WGs[e][3],w4=WGs[e][4],w5=WGs[e][5];
        #pragma unroll
        for (int q=0;q<4;q++){
            F2 l = f2fma(px[q],w0, f2fma(py[q],w1, f2fma(pz[q],w2,
                   f2fma(vx[q],w3, f2fma(vy[q],w4,
                   __builtin_elementwise_fma(vz[q], f2splat(w5), f2splat(0.f)))))));
            int j0 = 2*q, j1 = 2*q+1;
            float lx = l.x, ly = l.y;
            if (lx > m0[j0]){ m1[j0]=m0[j0]; i1[j0]=i0[j0]; m0[j0]=lx; i0[j0]=e; }
            else if (lx > m1[j0]){ m1[j0]=lx; i1[j0]=e; }
            if (ly > m0[j1]){ m1[j1]=m0[j1]; i1[j1]=i0[j1]; m0[j1]=ly; i0[j1]=e; }
            else if (ly > m1[j1]){ m1[j1]=ly; i1[j1]=e; }
        }
    }
    #pragma unroll
    for (int j=0;j<8;j++){
        float g0 = __fdividef(1.0f, 1.0f + __expf(m1[j]-m0[j]));
        g0a[base + j*256] = g0;
        eea[base + j*256] = i0[j] | (i1[j] << 8);
    }
}

// ---------------- kernel 2: transmittance scan -> keep mask + expert counts ----------------
__global__ __launch_bounds__(256) void k_scan0(const float* __restrict__ alpha0,
                                               const int* __restrict__ eea,
                                               const int* __restrict__ ray_off,
                                               unsigned char* __restrict__ keep,
                                               int* __restrict__ cntA)
{
    __shared__ int wcs[4][8];
    int t = threadIdx.x, lane = t & 63, w = t >> 6;
    int wid = blockIdx.x*4 + w;                      // wave = ray
    int c[8];
    #pragma unroll
    for (int e=0;e<8;e++) c[e]=0;
    int s = ray_off[wid], e = ray_off[wid+1];
    float carry = 1.f;
    for (int ch = s; ch < e; ch += 64){
        int p = ch + lane;
        bool in = p < e;
        float a = in ? alpha0[p] : 0.f;
        int  ee = in ? eea[p] : 0;
        float incl = 1.f - a;
        #pragma unroll
        for (int d=1; d<64; d<<=1){ float tt = __shfl_up(incl, d); if (lane >= d) incl *= tt; }
        float excl = __shfl_up(incl, 1); if (lane == 0) excl = 1.f;
        float w0 = a * carry * excl;
        int k = (in && w0 > THRESH) ? 1 : 0;
        if (in) keep[p] = (unsigned char)k;
        int e0 = ee & 255, e1 = (ee >> 8) & 255;
        #pragma unroll
        for (int x=0;x<8;x++){
            unsigned long long m0 = __ballot(k && e0==x);
            unsigned long long m1 = __ballot(k && e1==x);
            c[x] += __popcll(m0) + __popcll(m1);
        }
        carry *= __shfl(incl, 63);
    }
    if (lane == 0){
        #pragma unroll
        for (int x=0;x<8;x++) wcs[w][x] = c[x];
    }
    __syncthreads();
    if (t < 8){
        int sum = wcs[0][t]+wcs[1][t]+wcs[2][t]+wcs[3][t];
        if (sum) atomicAdd(&cntA[t], sum);
    }
}

// ---------------- kernel 3: fill entries (ballot-ranked; local prefix of cntA) ----------------
// entry.x = pid | (slot << 30), entry.y = gate weight bits
__global__ __launch_bounds__(256) void k_fill(const unsigned char* __restrict__ keep,
                                              const float* __restrict__ g0a,
                                              const int* __restrict__ eea,
                                              const int* __restrict__ cntA,
                                              int* __restrict__ curA,
                                              int2* __restrict__ ent)
{
    __shared__ int wc[4][8];
    __shared__ int wb[4][8];
    __shared__ int sOff[8];
    int t = threadIdx.x, lane = t & 63, w = t >> 6;
    unsigned long long lt = (1ull << lane) - 1ull;
    int base = blockIdx.x * 2048;

    int c[8];
    #pragma unroll
    for (int e=0;e<8;e++) c[e]=0;
    for (int j=0;j<8;j++){
        int p = base + (j*4 + w)*64 + lane;
        int k = keep[p];
        int ee = eea[p];
        int e0 = ee & 255, e1 = (ee >> 8) & 255;
        #pragma unroll
        for (int e=0;e<8;e++){
            unsigned long long m0 = __ballot(k && e0==e);
            unsigned long long m1 = __ballot(k && e1==e);
            c[e] += __popcll(m0) + __popcll(m1);
        }
    }
    if (lane == 0){
        #pragma unroll
        for (int e=0;e<8;e++) wc[w][e] = c[e];
    }
    if (t == 0){                                // local exclusive prefix of cntA
        int acc = 0;
        for (int e=0;e<8;e++){ sOff[e] = acc; acc += cntA[e]; }
    }
    __syncthreads();
    if (t < 8){
        int tot = wc[0][t]+wc[1][t]+wc[2][t]+wc[3][t];
        int b = sOff[t] + (tot ? atomicAdd(&curA[t], tot) : 0);
        wb[0][t] = b; b += wc[0][t];
        wb[1][t] = b; b += wc[1][t];
        wb[2][t] = b; b += wc[2][t];
        wb[3][t] = b;
    }
    __syncthreads();

    int cur[8];
    #pragma unroll
    for (int e=0;e<8;e++) cur[e] = wb[w][e];
    for (int j=0;j<8;j++){
        int p = base + (j*4 + w)*64 + lane;
        int k = keep[p];
        float g0 = g0a[p];
        int ee = eea[p];
        int e0 = ee & 255, e1 = (ee >> 8) & 255;
        #pragma unroll
        for (int e=0;e<8;e++){
            unsigned long long m0 = __ballot(k && e0==e);
            unsigned long long m1 = __ballot(k && e1==e);
            if (k && e0==e)
                ent[cur[e] + __popcll(m0 & lt)] = make_int2(p, __float_as_int(g0));
            if (k && e1==e)
                ent[cur[e] + __popcll(m0) + __popcll(m1 & lt)] =
                    make_int2(p | (1 << 30), __float_as_int(1.0f - g0));
            cur[e] += __popcll(m0) + __popcll(m1);
        }
    }
}

// ---------------- kernel 4: expert MLPs (scalar-F2 core, vd-cached loads) ----------------
// 512 blocks/expert, 256 threads, 4 F2 pairs/thread.
// NOTE: live state ~80 VGPRs max — 16 entries/thread spilled to scratch in R4.
// MFMA variant (R7) measured SLOWER (99 vs 91 us): K=7/N=4 tile waste + shfl/LDS
// wrapper overhead beats the MFMA gain at this tiny GEMM shape. Scalar it is.
__global__ __launch_bounds__(256) void k_expert(
    const int2* __restrict__ ent, const int* __restrict__ cntA,
    const float* __restrict__ pts, const float4* __restrict__ vd,
    const float* __restrict__ We1, const float* __restrict__ be1,
    const float* __restrict__ Wrgb, const float* __restrict__ Walpha,
    float4* __restrict__ res)
{
    int e    = blockIdx.x >> 9;
    int bi   = blockIdx.x & 511;
    int base = bi * 2048;

    __shared__ float4 WA[128];   // We1[e][0..3][i]
    __shared__ float4 WB[128];   // We1[e][4][i], We1[e][5][i], be1[e][i], Walpha[e][i]
    __shared__ float4 WC[128];   // Wrgb[e][i][0..2], 0
    __shared__ int sSeg[2];      // {segment start, n}
    int t = threadIdx.x;
    if (t < 128){
        const float* w = We1 + e*768;
        WA[t] = make_float4(w[t], w[128+t], w[256+t], w[384+t]);
        WB[t] = make_float4(w[512+t], w[640+t], be1[e*128+t], Walpha[e*128+t]);
        const float* wr = Wrgb + e*384 + 3*t;
        WC[t] = make_float4(wr[0], wr[1], wr[2], 0.f);
    }
    if (t == 0){
        int acc = 0;
        for (int i=0;i<e;i++) acc += cntA[i];
        sSeg[0] = acc; sSeg[1] = cntA[e];
    }
    __syncthreads();
    int n = sSeg[1];
    if (base >= n) return;                      // uniform exit (post-barrier)
    const int2* eb = ent + sSeg[0];

    F2 x0[4],x1[4],x2[4],x3[4],x4[4],x5[4];
    F2 ar[4],ag[4],ab[4],aa[4];
    #pragma unroll
    for (int pr=0;pr<4;pr++){
        int idx0 = base + t + (2*pr)*256, idx1 = idx0 + 256;
        int2 r0 = (idx0 < n) ? eb[idx0] : make_int2(0,0);
        int2 r1 = (idx1 < n) ? eb[idx1] : make_int2(0,0);
        int p0 = r0.x & 0x0FFFFFFF, p1 = r1.x & 0x0FFFFFFF;
        x0[pr] = (F2){pts[3*p0],   pts[3*p1]};
        x1[pr] = (F2){pts[3*p0+1], pts[3*p1+1]};
        x2[pr] = (F2){pts[3*p0+2], pts[3*p1+2]};
        float4 v0 = vd[p0], v1 = vd[p1];
        x3[pr] = (F2){v0.x, v1.x};
        x4[pr] = (F2){v0.y, v1.y};
        x5[pr] = (F2){v0.z, v1.z};
        ar[pr] = f2splat(0.f); ag[pr] = f2splat(0.f);
        ab[pr] = f2splat(0.f); aa[pr] = f2splat(0.f);
    }
    #pragma unroll 2
    for (int i=0;i<128;i++){
        float4 wa = WA[i], wb = WB[i], wc = WC[i];
        #pragma unroll
        for (int pr=0;pr<4;pr++){
            F2 h = f2fma(x0[pr],wa.x, f2fma(x1[pr],wa.y, f2fma(x2[pr],wa.z,
                   f2fma(x3[pr],wa.w, f2fma(x4[pr],wb.x, f2fma(x5[pr],wb.y,
                   f2splat(wb.z)))))));
            h = __builtin_elementwise_max(h, f2splat(0.f));
            ar[pr] = f2fma(h, wc.x, ar[pr]);
            ag[pr] = f2fma(h, wc.y, ag[pr]);
            ab[pr] = f2fma(h, wc.z, ab[pr]);
            aa[pr] = f2fma(h, wb.w, aa[pr]);
        }
    }
    #pragma unroll
    for (int pr=0;pr<4;pr++){
        #pragma unroll
        for (int sel=0; sel<2; sel++){
            int idx = base + t + (2*pr+sel)*256;
            if (idx < n){
                int2 rec = eb[idx];                 // reload g/pid (keeps loop VGPRs low)
                float vr = sel ? ar[pr].y : ar[pr].x;
                float vg = sel ? ag[pr].y : ag[pr].x;
                float vb = sel ? ab[pr].y : ab[pr].x;
                float va = sel ? aa[pr].y : aa[pr].x;
                float sr = __fdividef(1.0f, 1.0f + __expf(-vr));
                float sg = __fdividef(1.0f, 1.0f + __expf(-vg));
                float sb = __fdividef(1.0f, 1.0f + __expf(-vb));
                float a  = raw2alpha_f(va);
                float g  = __int_as_float(rec.y);
                int pp   = rec.x & 0x0FFFFFFF;
                int slot = ((unsigned)rec.x) >> 30;
                res[2*(size_t)pp + slot] = make_float4(g*sr, g*sg, g*sb, g*a);
            }
        }
    }
}

// ---------------- kernel 5: final per-ray composite ----------------
__global__ __launch_bounds__(256) void k_scan1(const float4* __restrict__ res,
                                               const unsigned char* __restrict__ keep,
                                               const int* __restrict__ ray_off,
                                               const float* __restrict__ bg,
                                               float* __restrict__ out)
{
    int wid  = (blockIdx.x*blockDim.x + threadIdx.x) >> 6;   // wave = ray
    int lane = threadIdx.x & 63;
    if (wid >= NRAYS) return;
    int s = ray_off[wid], e = ray_off[wid+1];
    float carry = 1.f;
    float accx = 0.f, accy = 0.f, accz = 0.f;
    for (int c = s; c < e; c += 64){
        int p = c + lane;
        float4 v = make_float4(0.f,0.f,0.f,0.f);
        if (p < e && keep[p]){
            float4 v0 = res[2*(size_t)p];
            float4 v1 = res[2*(size_t)p + 1];
            v = make_float4(v0.x+v1.x, v0.y+v1.y, v0.z+v1.z, v0.w+v1.w);
        }
        float a = v.w;
        float incl = 1.f - a;
        #pragma unroll
        for (int d=1; d<64; d<<=1){ float tt = __shfl_up(incl, d); if (lane >= d) incl *= tt; }
        float excl = __shfl_up(incl, 1); if (lane == 0) excl = 1.f;
        float w = a * carry * excl;
        accx = fmaf(w, v.x, accx);
        accy = fmaf(w, v.y, accy);
        accz = fmaf(w, v.z, accz);
        carry *= __shfl(incl, 63);
    }
    #pragma unroll
    for (int d=32; d; d>>=1){
        accx += __shfl_xor(accx, d);
        accy += __shfl_xor(accy, d);
        accz += __shfl_xor(accz, d);
    }
    if (lane == 0){
        out[3*wid+0] = accx + carry*bg[0];
        out[3*wid+1] = accy + carry*bg[1];
        out[3*wid+2] = accz + carry*bg[2];
    }
}

extern "C" void kernel_launch(void* const* d_in, const int* in_sizes, int n_in,
                              void* d_out, int out_size, void* d_ws, size_t ws_size,
                              hipStream_t stream)
{
    const float* pts    = (const float*)d_in[0];
    const float* vdirs  = (const float*)d_in[1];
    const float* bg     = (const float*)d_in[2];
    const float* Wd1    = (const float*)d_in[3];
    const float* bd1    = (const float*)d_in[4];
    const float* Wd2    = (const float*)d_in[5];
    const float* Wg     = (const float*)d_in[6];
    const float* We1    = (const float*)d_in[7];
    const float* be1    = (const float*)d_in[8];
    const float* Wrgb   = (const float*)d_in[9];
    const float* Walpha = (const float*)d_in[10];
    const int*   ray_id = (const int*)d_in[11];
    float* out = (float*)d_out;

    char* ws = (char*)d_ws;
    size_t off = 0;
    float* alpha0        = (float*)(ws + off); off += (size_t)PTOT*4;       // 4MB
    float* g0a           = (float*)(ws + off); off += (size_t)PTOT*4;       // 4MB
    int*   eea           = (int*)  (ws + off); off += (size_t)PTOT*4;       // 4MB
    unsigned char* keep  = (unsigned char*)(ws + off); off += (size_t)PTOT; // 1MB
    int*   ray_off       = (int*)  (ws + off); off += 33024;                // 8193+ ints
    int*   cntA          = (int*)  (ws + off); off += 256;
    int*   curA          = (int*)  (ws + off); off += 256;
    off = (off + 255) & ~(size_t)255;
    float4* vd           = (float4*)(ws + off); off += (size_t)PTOT*16;     // 16MB
    int2*  ent           = (int2*) (ws + off); off += (size_t)2*PTOT*8;     // 16MB
    float4* res          = (float4*)(ws + off); off += ((size_t)2*PTOT+2)*16; // 32MB

    hipMemsetAsync(cntA, 0, 512, stream);   // cntA + curA (adjacent)

    k_point <<<PTOT/2048, 256, 0, stream>>>(pts, vdirs, ray_id, Wd1, bd1, Wd2, Wg,
                                            alpha0, g0a, eea, vd, ray_off);
    k_scan0 <<<NRAYS/4, 256, 0, stream>>>(alpha0, eea, ray_off, keep, cntA);
    k_fill  <<<PTOT/2048, 256, 0, stream>>>(keep, g0a, eea, cntA, curA, ent);
    k_expert<<<8*512, 256, 0, stream>>>(ent, cntA, pts, vd,
                                        We1, be1, Wrgb, Walpha, res);
    k_scan1 <<<NRAYS*64/256, 256, 0, stream>>>(res, keep, ray_off, bg, out);
}